// Round 11
// baseline (694.098 us; speedup 1.0000x reference)
//
#include <hip/hip_runtime.h>

#define NPTS 4096
#define NBATCH 8

typedef __attribute__((ext_vector_type(8))) short short8v;   // 8 bf16 = 4 VGPR
typedef __attribute__((ext_vector_type(4))) float f32x4;

__device__ __forceinline__ unsigned fenc(float f) {
  unsigned u = __float_as_uint(f);
  return (u & 0x80000000u) ? ~u : (u | 0x80000000u);
}
__device__ __forceinline__ float fdec(unsigned e) {
  unsigned u = (e & 0x80000000u) ? (e ^ 0x80000000u) : ~e;
  return __uint_as_float(u);
}
__device__ __forceinline__ float dot4(float4 a, float4 b) {
  return a.x * b.x + a.y * b.y + a.z * b.z + a.w * b.w;
}
__device__ __forceinline__ unsigned short f2bf(float f) {   // RNE float->bf16
  unsigned u = __float_as_uint(f);
  return (unsigned short)((u + 0x7fffu + ((u >> 16) & 1u)) >> 16);
}

// -------- Kernel 0a: pack cw2 [1024][128] -> bf16 MFMA B-fragments ----------
// frag (nt,ks,lane): 8 bf16 of cw2[n = nt*16 + (l&15)][k = ks*32 + (l>>4)*8 + j]
__global__ __launch_bounds__(256)
void k_wb(const float* __restrict__ cw2, unsigned short* __restrict__ cw2B) {
  int tid = blockIdx.x * 256 + threadIdx.x;   // 0..16383 = (nt*4+ks)*64+l
  int l = tid & 63, ks = (tid >> 6) & 3, nt = tid >> 8;
  int n = nt * 16 + (l & 15);
  int kb = ks * 32 + (l >> 4) * 8;
  const float* src = cw2 + (size_t)n * 128 + kb;
  unsigned short* dst = cw2B + (size_t)tid * 8;
#pragma unroll
  for (int j = 0; j < 8; j++) dst[j] = f2bf(src[j]);
}

// ---------------- Kernel 0b: pack pts -> {x,y,z,|p|^2} float4 ----------------
__global__ __launch_bounds__(256)
void k_pack(const float* __restrict__ pts, float4* __restrict__ pts4) {
  int i = blockIdx.x * 256 + threadIdx.x;     // over NBATCH*NPTS
  float x = pts[3 * i], y = pts[3 * i + 1], z = pts[3 * i + 2];
  pts4[i] = make_float4(x, y, z, x * x + y * y + z * z);
}

// ---------------- Kernel 1: exact 16-NN + covariance features ----------------
// 512 threads = 128 queries x 4 candidate-segments; scalarized global stream;
// per-thread sorted top-16 + LDS append buffer + bitonic merges. (round-8, verified)
__global__ __launch_bounds__(512)
void k_knn(const float4* __restrict__ pts4, int* __restrict__ idxo,
           float* __restrict__ x0) {
  __shared__ float4 sp[NPTS];                 // 64 KB
  __shared__ float bufd[16][512];             // 32 KB
  __shared__ unsigned short bufi[16][512];    // 16 KB

  const int b = blockIdx.x >> 5;
  const int ch = blockIdx.x & 31;
  const float4* pb4 = pts4 + (size_t)b * NPTS;
  for (int i = threadIdx.x; i < NPTS; i += 512) sp[i] = pb4[i];
  __syncthreads();

  const int t = threadIdx.x;
  const int tq = t & 127;
  const int seg = __builtin_amdgcn_readfirstlane(t >> 7);  // wave-uniform
  const int q = ch * 128 + tq;
  const float4 qp = sp[q];
  const float qs = qp.w;

  float td[16];
  int ti[16];
#pragma unroll
  for (int j = 0; j < 16; j++) { td[j] = 3.0e38f; ti[j] = 0; }
  float worst = 3.0e38f;
  int cnt = 0;

  auto merge = [&]() {
    float bd[16];
    int bi[16];
#pragma unroll
    for (int j = 0; j < 16; j++) {
      bool v = j < cnt;
      float dv = bufd[j][t];
      int iv = (int)bufi[j][t];
      bd[j] = v ? dv : 3.0e38f;
      bi[j] = v ? iv : 0;
    }
    cnt = 0;
#pragma unroll
    for (int k = 2; k <= 16; k <<= 1) {
#pragma unroll
      for (int j = k >> 1; j > 0; j >>= 1) {
#pragma unroll
        for (int i = 0; i < 16; i++) {
          int l = i ^ j;
          if (l > i) {
            bool dir = ((i & k) == 0);
            bool sw = dir ? (bd[i] > bd[l]) : (bd[i] < bd[l]);
            float fd = sw ? bd[l] : bd[i];
            float fl = sw ? bd[i] : bd[l];
            int gd = sw ? bi[l] : bi[i];
            int gl = sw ? bi[i] : bi[l];
            bd[i] = fd; bd[l] = fl; bi[i] = gd; bi[l] = gl;
          }
        }
      }
    }
#pragma unroll
    for (int i = 0; i < 16; i++) {
      int l = 15 - i;
      bool sw = bd[l] < td[i];
      td[i] = sw ? bd[l] : td[i];
      ti[i] = sw ? bi[l] : ti[i];
    }
#pragma unroll
    for (int j = 8; j > 0; j >>= 1) {
#pragma unroll
      for (int i = 0; i < 16; i++) {
        int l = i ^ j;
        if (l > i) {
          bool sw = td[i] > td[l];
          float fd = sw ? td[l] : td[i];
          float fl = sw ? td[i] : td[l];
          int gd = sw ? ti[l] : ti[i];
          int gl = sw ? ti[i] : ti[l];
          td[i] = fd; td[l] = fl; ti[i] = gd; ti[l] = gl;
        }
      }
    }
    worst = td[15];
  };

  const float4* ps = pb4 + seg * 1024;
  const int base = seg * 1024;
  for (int i0 = 0; i0 < 1024; i0 += 8) {
    float4 c[8];
#pragma unroll
    for (int u = 0; u < 8; u++) c[u] = ps[i0 + u];
    float d[8];
#pragma unroll
    for (int u = 0; u < 8; u++)
      d[u] = (qs + c[u].w) - 2.0f * (qp.x * c[u].x + qp.y * c[u].y + qp.z * c[u].z);
#pragma unroll
    for (int u = 0; u < 8; u++) {
      if (d[u] < worst) {
        bufd[cnt][t] = d[u];
        bufi[cnt][t] = (unsigned short)(base + i0 + u);
        cnt++;
      }
      if (u == 3 && __any(cnt >= 13)) merge();
    }
    if (__any(cnt >= 13)) merge();
  }
  if (__any(cnt > 0)) merge();

#pragma unroll
  for (int j = 0; j < 16; j++) { bufd[j][t] = td[j]; bufi[j][t] = (unsigned short)ti[j]; }
  __syncthreads();
  if (t < 128) {
#pragma unroll
    for (int s = 1; s < 4; s++) {
      float bd[16];
      int bi[16];
#pragma unroll
      for (int j = 0; j < 16; j++) {
        bd[j] = bufd[j][t + 128 * s];
        bi[j] = (int)bufi[j][t + 128 * s];
      }
#pragma unroll
      for (int i = 0; i < 16; i++) {
        int l = 15 - i;
        bool sw = bd[l] < td[i];
        td[i] = sw ? bd[l] : td[i];
        ti[i] = sw ? bi[l] : ti[i];
      }
#pragma unroll
      for (int j = 8; j > 0; j >>= 1) {
#pragma unroll
        for (int i = 0; i < 16; i++) {
          int l = i ^ j;
          if (l > i) {
            bool sw2 = td[i] > td[l];
            float fd = sw2 ? td[l] : td[i];
            float fl = sw2 ? td[i] : td[l];
            int gd = sw2 ? ti[l] : ti[i];
            int gl = sw2 ? ti[i] : ti[l];
            td[i] = fd; td[l] = fl; ti[i] = gd; ti[l] = gl;
          }
        }
      }
    }

    float nx[16], ny[16], nz[16];
    float mx = 0.f, my = 0.f, mz = 0.f;
#pragma unroll
    for (int k = 0; k < 16; k++) {
      float4 c = sp[ti[k]];
      nx[k] = c.x; ny[k] = c.y; nz[k] = c.z;
      mx += c.x; my += c.y; mz += c.z;
    }
    mx *= 0.0625f; my *= 0.0625f; mz *= 0.0625f;
    float c00 = 0, c01 = 0, c02 = 0, c11 = 0, c12 = 0, c22 = 0;
#pragma unroll
    for (int k = 0; k < 16; k++) {
      float dx = nx[k] - mx, dy = ny[k] - my, dz = nz[k] - mz;
      c00 += dx * dx; c01 += dx * dy; c02 += dx * dz;
      c11 += dy * dy; c12 += dy * dz; c22 += dz * dz;
    }
    size_t row = (size_t)b * NPTS + q;
    float* xo = x0 + row * 12;
    xo[0] = qp.x; xo[1] = qp.y; xo[2] = qp.z;
    xo[3] = c00;  xo[4] = c01;  xo[5] = c02;
    xo[6] = c01;  xo[7] = c11;  xo[8] = c12;
    xo[9] = c02;  xo[10] = c12; xo[11] = c22;
    int* io = idxo + row * 16;
#pragma unroll
    for (int k = 0; k < 16; k++) io[k] = ti[k];
  }
}

// ---------------- Kernel 2: MLP1 12->64->64->64 (relu each) ------------------
__global__ __launch_bounds__(128)
void k_mlp1(const float* __restrict__ x0,
            const float* __restrict__ w1, const float* __restrict__ b1,
            const float* __restrict__ w2, const float* __restrict__ b2,
            const float* __restrict__ w3, const float* __restrict__ b3,
            float* __restrict__ h3o) {
  __shared__ float s1[64 * 12], s2[64 * 64], s3[64 * 64];
  __shared__ float sb1[64], sb2[64], sb3[64];
  for (int i = threadIdx.x; i < 64 * 12; i += 128) s1[i] = w1[i];
  for (int i = threadIdx.x; i < 64 * 64; i += 128) { s2[i] = w2[i]; s3[i] = w3[i]; }
  if (threadIdx.x < 64) {
    sb1[threadIdx.x] = b1[threadIdx.x];
    sb2[threadIdx.x] = b2[threadIdx.x];
    sb3[threadIdx.x] = b3[threadIdx.x];
  }
  __syncthreads();

  size_t p = (size_t)blockIdx.x * 128 + threadIdx.x;
  const float4* xv = (const float4*)(x0 + p * 12);
  float4 xa = xv[0], xb = xv[1], xc = xv[2];

  float h[64];
#pragma unroll
  for (int o = 0; o < 64; o++) {
    const float4* wr = (const float4*)(s1 + o * 12);
    float a = sb1[o] + dot4(wr[0], xa) + dot4(wr[1], xb) + dot4(wr[2], xc);
    h[o] = fmaxf(a, 0.f);
  }
  float g[64];
#pragma unroll
  for (int o = 0; o < 64; o++) {
    float a = sb2[o];
    const float4* wr = (const float4*)(s2 + o * 64);
#pragma unroll
    for (int c4 = 0; c4 < 16; c4++) {
      float4 w = wr[c4];
      a += w.x * h[4 * c4] + w.y * h[4 * c4 + 1] + w.z * h[4 * c4 + 2] + w.w * h[4 * c4 + 3];
    }
    g[o] = fmaxf(a, 0.f);
  }
  float* out = h3o + p * 64;
  for (int o = 0; o < 64; o++) {
    float a = sb3[o];
    const float4* wr = (const float4*)(s3 + o * 64);
#pragma unroll
    for (int c4 = 0; c4 < 16; c4++) {
      float4 w = wr[c4];
      a += w.x * g[4 * c4] + w.y * g[4 * c4 + 1] + w.z * g[4 * c4 + 2] + w.w * g[4 * c4 + 3];
    }
    out[o] = fmaxf(a, 0.f);
  }
}

// -------- Kernel 3: maxpool(h3,idx) -> lw1 (lin) -> relu(cw1) -> z[...,128] --
__global__ __launch_bounds__(128)
void k_graph1(const float* __restrict__ h3, const int* __restrict__ idx,
              const float* __restrict__ lw1, const float* __restrict__ lb1,
              const float* __restrict__ cw1, const float* __restrict__ cb1,
              float* __restrict__ z) {
  __shared__ float sl[64 * 64], sc[128 * 64];
  __shared__ float sbl[64], sbc[128];
  for (int i = threadIdx.x; i < 64 * 64; i += 128) sl[i] = lw1[i];
  for (int i = threadIdx.x; i < 128 * 64; i += 128) sc[i] = cw1[i];
  if (threadIdx.x < 64) sbl[threadIdx.x] = lb1[threadIdx.x];
  if (threadIdx.x < 128) sbc[threadIdx.x] = cb1[threadIdx.x];
  __syncthreads();

  size_t p = (size_t)blockIdx.x * 128 + threadIdx.x;
  int b = (int)(p >> 12);
  const int* ip = idx + p * 16;

  float m[64];
#pragma unroll
  for (int c = 0; c < 64; c++) m[c] = -3.0e38f;
  for (int k = 0; k < 16; k++) {
    const float4* nb = (const float4*)(h3 + (((size_t)b << 12) + ip[k]) * 64);
#pragma unroll
    for (int c4 = 0; c4 < 16; c4++) {
      float4 v = nb[c4];
      m[4 * c4]     = fmaxf(m[4 * c4], v.x);
      m[4 * c4 + 1] = fmaxf(m[4 * c4 + 1], v.y);
      m[4 * c4 + 2] = fmaxf(m[4 * c4 + 2], v.z);
      m[4 * c4 + 3] = fmaxf(m[4 * c4 + 3], v.w);
    }
  }
  float y[64];
#pragma unroll
  for (int o = 0; o < 64; o++) {
    float a = sbl[o];
    const float4* wr = (const float4*)(sl + o * 64);
#pragma unroll
    for (int c4 = 0; c4 < 16; c4++) {
      float4 w = wr[c4];
      a += w.x * m[4 * c4] + w.y * m[4 * c4 + 1] + w.z * m[4 * c4 + 2] + w.w * m[4 * c4 + 3];
    }
    y[o] = a;   // no relu on lw1
  }
  float* zo = z + p * 128;
  for (int o = 0; o < 128; o++) {
    float a = sbc[o];
    const float4* wr = (const float4*)(sc + o * 64);
#pragma unroll
    for (int c4 = 0; c4 < 16; c4++) {
      float4 w = wr[c4];
      a += w.x * y[4 * c4] + w.y * y[4 * c4 + 1] + w.z * y[4 * c4 + 2] + w.w * y[4 * c4 + 3];
    }
    zo[o] = fmaxf(a, 0.f);
  }
}

// ------ Kernel 4: maxpool(z,idx) -> lw2 (fp32) -> cw2 (bf16 MFMA) -> max -----
// block = 64 points of one batch; 4 waves. LDS 48 KB -> 3 blocks/CU.
__global__ __launch_bounds__(256)
void k_graph2(const float* __restrict__ z, const int* __restrict__ idx,
              const float* __restrict__ lw2, const float* __restrict__ lb2,
              const unsigned short* __restrict__ cw2B, const float* __restrict__ cb2,
              unsigned* __restrict__ gacc) {
  __shared__ float smT[128][64];                    // [channel][point] 32 KB
  __shared__ alignas(16) unsigned short stb[64 * 128];  // bf16, XOR-swizzled 16 KB

  const int b = blockIdx.x >> 6;
  const int pbase = (blockIdx.x & 63) * 64;
  const int t = threadIdx.x;

  // Phase A: neighbor maxpool of z -> smT
  {
    const int pl = t & 63, cg = t >> 6;
    size_t p = (size_t)b * NPTS + pbase + pl;
    const int* ip = idx + p * 16;
    float mv[32];
#pragma unroll
    for (int c = 0; c < 32; c++) mv[c] = -3.0e38f;
    for (int k = 0; k < 16; k++) {
      const float4* nb = (const float4*)(z + ((size_t)b * NPTS + ip[k]) * 128 + cg * 32);
#pragma unroll
      for (int c4 = 0; c4 < 8; c4++) {
        float4 v = nb[c4];
        mv[4 * c4]     = fmaxf(mv[4 * c4], v.x);
        mv[4 * c4 + 1] = fmaxf(mv[4 * c4 + 1], v.y);
        mv[4 * c4 + 2] = fmaxf(mv[4 * c4 + 2], v.z);
        mv[4 * c4 + 3] = fmaxf(mv[4 * c4 + 3], v.w);
      }
    }
#pragma unroll
    for (int c = 0; c < 32; c++) smT[cg * 32 + c][pl] = mv[c];
  }
  __syncthreads();

  // Phase B (fp32): ST[p][o] = lb2[o] + lw2[o][:].m[p][:]; emit bf16 swizzled
  {
    const int pl = t & 63, og = t >> 6;
    float acc[32];
#pragma unroll
    for (int oi = 0; oi < 32; oi++) acc[oi] = lb2[og * 32 + oi];
    for (int cb = 0; cb < 4; cb++) {
      float mr[32];
#pragma unroll
      for (int j = 0; j < 32; j++) mr[j] = smT[cb * 32 + j][pl];
#pragma unroll
      for (int oi = 0; oi < 32; oi++) {
        const float4* wr = (const float4*)(lw2 + (size_t)(og * 32 + oi) * 128 + cb * 32);
#pragma unroll
        for (int j4 = 0; j4 < 8; j4++) {
          float4 w = wr[j4];
          acc[oi] += w.x * mr[4 * j4] + w.y * mr[4 * j4 + 1] + w.z * mr[4 * j4 + 2] + w.w * mr[4 * j4 + 3];
        }
      }
    }
#pragma unroll
    for (int e = 0; e < 4; e++) {
      short8v v;
#pragma unroll
      for (int j = 0; j < 8; j++) v[j] = (short)f2bf(acc[e * 8 + j]);
      int bc = (og * 64 + e * 16) ^ ((pl & 7) << 4);   // byte col, swizzled
      *(short8v*)((char*)stb + pl * 256 + bc) = v;
    }
  }
  __syncthreads();

  // Phase C (bf16 MFMA): U = ST x cw2^T (+cb2); col-max over 64 pts; atomicMax.
  // A row = lane&15, B col = lane&15, same k-enumeration on both sides (exact).
  // D: col = lane&15 (n), row = (lane>>4)*4 + reg (m)  [m89-verified].
  {
    const int wv = t >> 6;          // wave: 16 n-tiles each
    const int l = t & 63;
    const int lr = l & 15;
    const int lg = l >> 4;
    short8v a[4][4];                // [m-tile][k-step]
#pragma unroll
    for (int mt = 0; mt < 4; mt++)
#pragma unroll
      for (int ks = 0; ks < 4; ks++) {
        int row = mt * 16 + lr;
        int bc = (ks * 64 + lg * 16) ^ ((row & 7) << 4);
        a[mt][ks] = *(const short8v*)((const char*)stb + row * 256 + bc);
      }
    const short8v* cb8 = (const short8v*)cw2B;
    float bmax[16];
#pragma unroll
    for (int i = 0; i < 16; i++) {
      const int nt = wv * 16 + i;
      short8v bf[4];
#pragma unroll
      for (int ks = 0; ks < 4; ks++) bf[ks] = cb8[(nt * 4 + ks) * 64 + l];
      float mm = -3.0e38f;
#pragma unroll
      for (int mt = 0; mt < 4; mt++) {
        f32x4 acc = {0.f, 0.f, 0.f, 0.f};
#pragma unroll
        for (int ks = 0; ks < 4; ks++)
          acc = __builtin_amdgcn_mfma_f32_16x16x32_bf16(a[mt][ks], bf[ks], acc, 0, 0, 0);
        mm = fmaxf(mm, fmaxf(fmaxf(acc[0], acc[1]), fmaxf(acc[2], acc[3])));
      }
      mm = fmaxf(mm, __shfl_xor(mm, 16));
      mm = fmaxf(mm, __shfl_xor(mm, 32));
      bmax[i] = mm + cb2[nt * 16 + lr];   // bias is col-constant: add after max
    }
    if (l < 16) {
#pragma unroll
      for (int i = 0; i < 16; i++)
        atomicMax(&gacc[b * 1024 + (wv * 16 + i) * 16 + l], fenc(bmax[i]));
    }
  }
}

// ---------------- Kernel 5: head MLP 1024 -> 512(relu) -> 512 ----------------
__global__ __launch_bounds__(512)
void k_head(const unsigned* __restrict__ gacc,
            const float* __restrict__ mw1, const float* __restrict__ mb1,
            const float* __restrict__ mw2, const float* __restrict__ mb2,
            float* __restrict__ out) {
  __shared__ float g[1024];
  __shared__ float h[512];
  const int b = blockIdx.x, t = threadIdx.x;
  for (int i = t; i < 1024; i += 512) g[i] = fdec(gacc[b * 1024 + i]);
  __syncthreads();
  float a = mb1[t];
  const float4* wr = (const float4*)(mw1 + (size_t)t * 1024);
  const float4* gv = (const float4*)g;
#pragma unroll 8
  for (int c4 = 0; c4 < 256; c4++) a += dot4(wr[c4], gv[c4]);
  h[t] = fmaxf(a, 0.f);
  __syncthreads();
  float a2 = mb2[t];
  const float4* wr2 = (const float4*)(mw2 + (size_t)t * 512);
  const float4* hv = (const float4*)h;
#pragma unroll 8
  for (int c4 = 0; c4 < 128; c4++) a2 += dot4(wr2[c4], hv[c4]);
  out[(size_t)b * 512 + t] = a2;
}

extern "C" void kernel_launch(void* const* d_in, const int* in_sizes, int n_in,
                              void* d_out, int out_size, void* d_ws, size_t ws_size,
                              hipStream_t stream) {
  const float* pts = (const float*)d_in[0];
  const float* w1  = (const float*)d_in[1];
  const float* b1  = (const float*)d_in[2];
  const float* w2  = (const float*)d_in[3];
  const float* b2  = (const float*)d_in[4];
  const float* w3  = (const float*)d_in[5];
  const float* b3  = (const float*)d_in[6];
  const float* lw1 = (const float*)d_in[7];
  const float* lb1 = (const float*)d_in[8];
  const float* cw1 = (const float*)d_in[9];
  const float* cb1 = (const float*)d_in[10];
  const float* lw2 = (const float*)d_in[11];
  const float* lb2 = (const float*)d_in[12];
  const float* cw2 = (const float*)d_in[13];
  const float* cb2 = (const float*)d_in[14];
  const float* mw1 = (const float*)d_in[15];
  const float* mb1 = (const float*)d_in[16];
  const float* mw2 = (const float*)d_in[17];
  const float* mb2 = (const float*)d_in[18];

  char* ws = (char*)d_ws;
  int*      idx  = (int*)(ws);                                    // 2 MB
  float*    x0   = (float*)(ws + 2097152);                        // 1.5 MB
  float*    h3   = (float*)(ws + 2097152 + 1572864);              // 8 MB
  float*    z    = (float*)(ws + 2097152 + 1572864 + 8388608);    // 16 MB
  unsigned* gacc = (unsigned*)(ws + 28835840);                    // 32 KB
  unsigned short* cw2B = (unsigned short*)(ws + 28835840 + 32768);// 256 KB
  float4*   pts4 = (float4*)(ws + 28835840 + 32768 + 262144);     // 512 KB

  hipMemsetAsync(gacc, 0, NBATCH * 1024 * sizeof(unsigned), stream);
  k_wb<<<64, 256, 0, stream>>>(cw2, cw2B);
  k_pack<<<(NBATCH * NPTS) / 256, 256, 0, stream>>>(pts, pts4);
  k_knn<<<NBATCH * (NPTS / 128), 512, 0, stream>>>(pts4, idx, x0);
  k_mlp1<<<(NBATCH * NPTS) / 128, 128, 0, stream>>>(x0, w1, b1, w2, b2, w3, b3, h3);
  k_graph1<<<(NBATCH * NPTS) / 128, 128, 0, stream>>>(h3, idx, lw1, lb1, cw1, cb1, z);
  k_graph2<<<NBATCH * (NPTS / 64), 256, 0, stream>>>(z, idx, lw2, lb2, cw2B, cb2, gacc);
  k_head<<<NBATCH, 512, 0, stream>>>(gacc, mw1, mb1, mw2, mb2, (float*)d_out);
}

// Round 12
// 520.449 us; speedup vs baseline: 1.3337x; 1.3337x over previous
//
#include <hip/hip_runtime.h>

#define NPTS 4096
#define NBATCH 8

typedef __attribute__((ext_vector_type(8))) short short8v;   // 8 bf16 = 4 VGPR
typedef __attribute__((ext_vector_type(4))) float f32x4;

__device__ __forceinline__ unsigned fenc(float f) {
  unsigned u = __float_as_uint(f);
  return (u & 0x80000000u) ? ~u : (u | 0x80000000u);
}
__device__ __forceinline__ float fdec(unsigned e) {
  unsigned u = (e & 0x80000000u) ? (e ^ 0x80000000u) : ~e;
  return __uint_as_float(u);
}
__device__ __forceinline__ float dot4(float4 a, float4 b) {
  return a.x * b.x + a.y * b.y + a.z * b.z + a.w * b.w;
}
__device__ __forceinline__ unsigned short f2bf(float f) {   // RNE float->bf16
  unsigned u = __float_as_uint(f);
  return (unsigned short)((u + 0x7fffu + ((u >> 16) & 1u)) >> 16);
}

// -------- Kernel 0a: pack cw2 [1024][128] -> bf16 MFMA B-fragments ----------
__global__ __launch_bounds__(256)
void k_wb(const float* __restrict__ cw2, unsigned short* __restrict__ cw2B) {
  int tid = blockIdx.x * 256 + threadIdx.x;   // 0..16383 = (nt*4+ks)*64+l
  int l = tid & 63, ks = (tid >> 6) & 3, nt = tid >> 8;
  int n = nt * 16 + (l & 15);
  int kb = ks * 32 + (l >> 4) * 8;
  const float* src = cw2 + (size_t)n * 128 + kb;
  unsigned short* dst = cw2B + (size_t)tid * 8;
#pragma unroll
  for (int j = 0; j < 8; j++) dst[j] = f2bf(src[j]);
}

// ---------------- Kernel 0b: pack pts -> {x,y,z,|p|^2} float4 ----------------
__global__ __launch_bounds__(256)
void k_pack(const float* __restrict__ pts, float4* __restrict__ pts4) {
  int i = blockIdx.x * 256 + threadIdx.x;     // over NBATCH*NPTS
  float x = pts[3 * i], y = pts[3 * i + 1], z = pts[3 * i + 2];
  pts4[i] = make_float4(x, y, z, x * x + y * y + z * z);
}

// ---------------- Kernel 1: exact 16-NN + covariance features ----------------
// 512 threads = 128 queries x 4 candidate-segments; scalarized global stream;
// per-thread sorted top-16 + LDS append buffer + bitonic merges. (verified r10)
__global__ __launch_bounds__(512)
void k_knn(const float4* __restrict__ pts4, int* __restrict__ idxo,
           float* __restrict__ x0) {
  __shared__ float4 sp[NPTS];                 // 64 KB
  __shared__ float bufd[16][512];             // 32 KB
  __shared__ unsigned short bufi[16][512];    // 16 KB

  const int b = blockIdx.x >> 5;
  const int ch = blockIdx.x & 31;
  const float4* pb4 = pts4 + (size_t)b * NPTS;
  for (int i = threadIdx.x; i < NPTS; i += 512) sp[i] = pb4[i];
  __syncthreads();

  const int t = threadIdx.x;
  const int tq = t & 127;
  const int seg = __builtin_amdgcn_readfirstlane(t >> 7);  // wave-uniform
  const int q = ch * 128 + tq;
  const float4 qp = sp[q];
  const float qs = qp.w;

  float td[16];
  int ti[16];
#pragma unroll
  for (int j = 0; j < 16; j++) { td[j] = 3.0e38f; ti[j] = 0; }
  float worst = 3.0e38f;
  int cnt = 0;

  auto merge = [&]() {
    float bd[16];
    int bi[16];
#pragma unroll
    for (int j = 0; j < 16; j++) {
      bool v = j < cnt;
      float dv = bufd[j][t];
      int iv = (int)bufi[j][t];
      bd[j] = v ? dv : 3.0e38f;
      bi[j] = v ? iv : 0;
    }
    cnt = 0;
#pragma unroll
    for (int k = 2; k <= 16; k <<= 1) {
#pragma unroll
      for (int j = k >> 1; j > 0; j >>= 1) {
#pragma unroll
        for (int i = 0; i < 16; i++) {
          int l = i ^ j;
          if (l > i) {
            bool dir = ((i & k) == 0);
            bool sw = dir ? (bd[i] > bd[l]) : (bd[i] < bd[l]);
            float fd = sw ? bd[l] : bd[i];
            float fl = sw ? bd[i] : bd[l];
            int gd = sw ? bi[l] : bi[i];
            int gl = sw ? bi[i] : bi[l];
            bd[i] = fd; bd[l] = fl; bi[i] = gd; bi[l] = gl;
          }
        }
      }
    }
#pragma unroll
    for (int i = 0; i < 16; i++) {
      int l = 15 - i;
      bool sw = bd[l] < td[i];
      td[i] = sw ? bd[l] : td[i];
      ti[i] = sw ? bi[l] : ti[i];
    }
#pragma unroll
    for (int j = 8; j > 0; j >>= 1) {
#pragma unroll
      for (int i = 0; i < 16; i++) {
        int l = i ^ j;
        if (l > i) {
          bool sw = td[i] > td[l];
          float fd = sw ? td[l] : td[i];
          float fl = sw ? td[i] : td[l];
          int gd = sw ? ti[l] : ti[i];
          int gl = sw ? ti[i] : ti[l];
          td[i] = fd; td[l] = fl; ti[i] = gd; ti[l] = gl;
        }
      }
    }
    worst = td[15];
  };

  const float4* ps = pb4 + seg * 1024;
  const int base = seg * 1024;
  for (int i0 = 0; i0 < 1024; i0 += 8) {
    float4 c[8];
#pragma unroll
    for (int u = 0; u < 8; u++) c[u] = ps[i0 + u];
    float d[8];
#pragma unroll
    for (int u = 0; u < 8; u++)
      d[u] = (qs + c[u].w) - 2.0f * (qp.x * c[u].x + qp.y * c[u].y + qp.z * c[u].z);
#pragma unroll
    for (int u = 0; u < 8; u++) {
      if (d[u] < worst) {
        bufd[cnt][t] = d[u];
        bufi[cnt][t] = (unsigned short)(base + i0 + u);
        cnt++;
      }
      if (u == 3 && __any(cnt >= 13)) merge();
    }
    if (__any(cnt >= 13)) merge();
  }
  if (__any(cnt > 0)) merge();

#pragma unroll
  for (int j = 0; j < 16; j++) { bufd[j][t] = td[j]; bufi[j][t] = (unsigned short)ti[j]; }
  __syncthreads();
  if (t < 128) {
#pragma unroll
    for (int s = 1; s < 4; s++) {
      float bd[16];
      int bi[16];
#pragma unroll
      for (int j = 0; j < 16; j++) {
        bd[j] = bufd[j][t + 128 * s];
        bi[j] = (int)bufi[j][t + 128 * s];
      }
#pragma unroll
      for (int i = 0; i < 16; i++) {
        int l = 15 - i;
        bool sw = bd[l] < td[i];
        td[i] = sw ? bd[l] : td[i];
        ti[i] = sw ? bi[l] : ti[i];
      }
#pragma unroll
      for (int j = 8; j > 0; j >>= 1) {
#pragma unroll
        for (int i = 0; i < 16; i++) {
          int l = i ^ j;
          if (l > i) {
            bool sw2 = td[i] > td[l];
            float fd = sw2 ? td[l] : td[i];
            float fl = sw2 ? td[i] : td[l];
            int gd = sw2 ? ti[l] : ti[i];
            int gl = sw2 ? ti[i] : ti[l];
            td[i] = fd; td[l] = fl; ti[i] = gd; ti[l] = gl;
          }
        }
      }
    }

    float nx[16], ny[16], nz[16];
    float mx = 0.f, my = 0.f, mz = 0.f;
#pragma unroll
    for (int k = 0; k < 16; k++) {
      float4 c = sp[ti[k]];
      nx[k] = c.x; ny[k] = c.y; nz[k] = c.z;
      mx += c.x; my += c.y; mz += c.z;
    }
    mx *= 0.0625f; my *= 0.0625f; mz *= 0.0625f;
    float c00 = 0, c01 = 0, c02 = 0, c11 = 0, c12 = 0, c22 = 0;
#pragma unroll
    for (int k = 0; k < 16; k++) {
      float dx = nx[k] - mx, dy = ny[k] - my, dz = nz[k] - mz;
      c00 += dx * dx; c01 += dx * dy; c02 += dx * dz;
      c11 += dy * dy; c12 += dy * dz; c22 += dz * dz;
    }
    size_t row = (size_t)b * NPTS + q;
    float* xo = x0 + row * 12;
    xo[0] = qp.x; xo[1] = qp.y; xo[2] = qp.z;
    xo[3] = c00;  xo[4] = c01;  xo[5] = c02;
    xo[6] = c01;  xo[7] = c11;  xo[8] = c12;
    xo[9] = c02;  xo[10] = c12; xo[11] = c22;
    int* io = idxo + row * 16;
#pragma unroll
    for (int k = 0; k < 16; k++) io[k] = ti[k];
  }
}

// ---------------- Kernel 2: MLP1 12->64->64->64 (relu each) ------------------
__global__ __launch_bounds__(128)
void k_mlp1(const float* __restrict__ x0,
            const float* __restrict__ w1, const float* __restrict__ b1,
            const float* __restrict__ w2, const float* __restrict__ b2,
            const float* __restrict__ w3, const float* __restrict__ b3,
            float* __restrict__ h3o) {
  __shared__ float s1[64 * 12], s2[64 * 64], s3[64 * 64];
  __shared__ float sb1[64], sb2[64], sb3[64];
  for (int i = threadIdx.x; i < 64 * 12; i += 128) s1[i] = w1[i];
  for (int i = threadIdx.x; i < 64 * 64; i += 128) { s2[i] = w2[i]; s3[i] = w3[i]; }
  if (threadIdx.x < 64) {
    sb1[threadIdx.x] = b1[threadIdx.x];
    sb2[threadIdx.x] = b2[threadIdx.x];
    sb3[threadIdx.x] = b3[threadIdx.x];
  }
  __syncthreads();

  size_t p = (size_t)blockIdx.x * 128 + threadIdx.x;
  const float4* xv = (const float4*)(x0 + p * 12);
  float4 xa = xv[0], xb = xv[1], xc = xv[2];

  float h[64];
#pragma unroll
  for (int o = 0; o < 64; o++) {
    const float4* wr = (const float4*)(s1 + o * 12);
    float a = sb1[o] + dot4(wr[0], xa) + dot4(wr[1], xb) + dot4(wr[2], xc);
    h[o] = fmaxf(a, 0.f);
  }
  float g[64];
#pragma unroll
  for (int o = 0; o < 64; o++) {
    float a = sb2[o];
    const float4* wr = (const float4*)(s2 + o * 64);
#pragma unroll
    for (int c4 = 0; c4 < 16; c4++) {
      float4 w = wr[c4];
      a += w.x * h[4 * c4] + w.y * h[4 * c4 + 1] + w.z * h[4 * c4 + 2] + w.w * h[4 * c4 + 3];
    }
    g[o] = fmaxf(a, 0.f);
  }
  float* out = h3o + p * 64;
  for (int o = 0; o < 64; o++) {
    float a = sb3[o];
    const float4* wr = (const float4*)(s3 + o * 64);
#pragma unroll
    for (int c4 = 0; c4 < 16; c4++) {
      float4 w = wr[c4];
      a += w.x * g[4 * c4] + w.y * g[4 * c4 + 1] + w.z * g[4 * c4 + 2] + w.w * g[4 * c4 + 3];
    }
    out[o] = fmaxf(a, 0.f);
  }
}

// -------- Kernel 3 (v2): 64-point tile, 4 threads/point, 8 waves/CU ----------
// maxpool(h3,idx) -> lw1 (lin) -> relu(cw1). LDS [ch][pt] => lane-consecutive,
// conflict-free. Weights read wave-uniform (scalarized via readfirstlane).
__global__ __launch_bounds__(256)
void k_graph1(const float* __restrict__ h3, const int* __restrict__ idx,
              const float* __restrict__ lw1, const float* __restrict__ lb1,
              const float* __restrict__ cw1, const float* __restrict__ cb1,
              float* __restrict__ z) {
  __shared__ float smc[64][64];   // [channel][point] 16 KB
  __shared__ float yc[64][64];    // [channel][point] 16 KB

  const int b = blockIdx.x >> 6;
  const int pbase = (blockIdx.x & 63) * 64;
  const int t = threadIdx.x;
  const int pl = t & 63;
  const int cg = __builtin_amdgcn_readfirstlane(t >> 6);   // wave-uniform group

  // Phase A: maxpool 16 channels (cg*16..) of point pl over its 16 neighbors
  {
    size_t p = (size_t)b * NPTS + pbase + pl;
    const int* ip = idx + p * 16;
    float mv[16];
#pragma unroll
    for (int c = 0; c < 16; c++) mv[c] = -3.0e38f;
    for (int k = 0; k < 16; k++) {
      const float4* nb = (const float4*)(h3 + (((size_t)b << 12) + ip[k]) * 64 + cg * 16);
#pragma unroll
      for (int c4 = 0; c4 < 4; c4++) {
        float4 v = nb[c4];
        mv[4 * c4]     = fmaxf(mv[4 * c4], v.x);
        mv[4 * c4 + 1] = fmaxf(mv[4 * c4 + 1], v.y);
        mv[4 * c4 + 2] = fmaxf(mv[4 * c4 + 2], v.z);
        mv[4 * c4 + 3] = fmaxf(mv[4 * c4 + 3], v.w);
      }
    }
#pragma unroll
    for (int c = 0; c < 16; c++) smc[cg * 16 + c][pl] = mv[c];
  }
  __syncthreads();

  // Phase B: y[cg*16+j] = lb1 + lw1_row . m   (weights wave-uniform)
  {
    float m[64];
#pragma unroll
    for (int c = 0; c < 64; c++) m[c] = smc[c][pl];
    for (int j = 0; j < 16; j++) {
      const float* wr = lw1 + (size_t)(cg * 16 + j) * 64;
      float a = lb1[cg * 16 + j];
#pragma unroll
      for (int c = 0; c < 64; c++) a += wr[c] * m[c];
      yc[cg * 16 + j][pl] = a;   // no relu on lw1
    }
  }
  __syncthreads();

  // Phase C: z[cg*32+o] = relu(cb1 + cw1_row . y)
  {
    float y[64];
#pragma unroll
    for (int c = 0; c < 64; c++) y[c] = yc[c][pl];
    size_t p = (size_t)b * NPTS + pbase + pl;
    float* zo = z + p * 128 + cg * 32;
    for (int o4 = 0; o4 < 8; o4++) {
      float r[4];
#pragma unroll
      for (int oi = 0; oi < 4; oi++) {
        int o = o4 * 4 + oi;
        const float* wr = cw1 + (size_t)(cg * 32 + o) * 64;
        float a = cb1[cg * 32 + o];
#pragma unroll
        for (int c = 0; c < 64; c++) a += wr[c] * y[c];
        r[oi] = fmaxf(a, 0.f);
      }
      *(float4*)(zo + o4 * 4) = make_float4(r[0], r[1], r[2], r[3]);
    }
  }
}

// ------ Kernel 4: maxpool(z,idx) -> lw2 (fp32) -> cw2 (bf16 MFMA) -> max -----
__global__ __launch_bounds__(256)
void k_graph2(const float* __restrict__ z, const int* __restrict__ idx,
              const float* __restrict__ lw2, const float* __restrict__ lb2,
              const unsigned short* __restrict__ cw2B, const float* __restrict__ cb2,
              unsigned* __restrict__ gacc) {
  __shared__ float smT[128][64];                    // [channel][point] 32 KB
  __shared__ alignas(16) unsigned short stb[64 * 128];  // bf16, XOR-swizzled 16 KB

  const int b = blockIdx.x >> 6;
  const int pbase = (blockIdx.x & 63) * 64;
  const int t = threadIdx.x;

  // Phase A: neighbor maxpool of z -> smT
  {
    const int pl = t & 63, cg = t >> 6;
    size_t p = (size_t)b * NPTS + pbase + pl;
    const int* ip = idx + p * 16;
    float mv[32];
#pragma unroll
    for (int c = 0; c < 32; c++) mv[c] = -3.0e38f;
    for (int k = 0; k < 16; k++) {
      const float4* nb = (const float4*)(z + ((size_t)b * NPTS + ip[k]) * 128 + cg * 32);
#pragma unroll
      for (int c4 = 0; c4 < 8; c4++) {
        float4 v = nb[c4];
        mv[4 * c4]     = fmaxf(mv[4 * c4], v.x);
        mv[4 * c4 + 1] = fmaxf(mv[4 * c4 + 1], v.y);
        mv[4 * c4 + 2] = fmaxf(mv[4 * c4 + 2], v.z);
        mv[4 * c4 + 3] = fmaxf(mv[4 * c4 + 3], v.w);
      }
    }
#pragma unroll
    for (int c = 0; c < 32; c++) smT[cg * 32 + c][pl] = mv[c];
  }
  __syncthreads();

  // Phase B (fp32): ST[p][o] = lb2[o] + lw2[o][:].m[p][:]; emit bf16 swizzled
  {
    const int pl = t & 63, og = t >> 6;
    float acc[32];
#pragma unroll
    for (int oi = 0; oi < 32; oi++) acc[oi] = lb2[og * 32 + oi];
    for (int cb = 0; cb < 4; cb++) {
      float mr[32];
#pragma unroll
      for (int j = 0; j < 32; j++) mr[j] = smT[cb * 32 + j][pl];
#pragma unroll
      for (int oi = 0; oi < 32; oi++) {
        const float4* wr = (const float4*)(lw2 + (size_t)(og * 32 + oi) * 128 + cb * 32);
#pragma unroll
        for (int j4 = 0; j4 < 8; j4++) {
          float4 w = wr[j4];
          acc[oi] += w.x * mr[4 * j4] + w.y * mr[4 * j4 + 1] + w.z * mr[4 * j4 + 2] + w.w * mr[4 * j4 + 3];
        }
      }
    }
#pragma unroll
    for (int e = 0; e < 4; e++) {
      short8v v;
#pragma unroll
      for (int j = 0; j < 8; j++) v[j] = (short)f2bf(acc[e * 8 + j]);
      int bc = (og * 64 + e * 16) ^ ((pl & 7) << 4);   // byte col, swizzled
      *(short8v*)((char*)stb + pl * 256 + bc) = v;
    }
  }
  __syncthreads();

  // Phase C (bf16 MFMA): U = ST x cw2^T (+cb2); col-max over 64 pts; atomicMax.
  {
    const int wv = t >> 6;          // wave: 16 n-tiles each
    const int l = t & 63;
    const int lr = l & 15;
    const int lg = l >> 4;
    short8v a[4][4];                // [m-tile][k-step]
#pragma unroll
    for (int mt = 0; mt < 4; mt++)
#pragma unroll
      for (int ks = 0; ks < 4; ks++) {
        int row = mt * 16 + lr;
        int bc = (ks * 64 + lg * 16) ^ ((row & 7) << 4);
        a[mt][ks] = *(const short8v*)((const char*)stb + row * 256 + bc);
      }
    const short8v* cb8 = (const short8v*)cw2B;
    float bmax[16];
#pragma unroll
    for (int i = 0; i < 16; i++) {
      const int nt = wv * 16 + i;
      short8v bf[4];
#pragma unroll
      for (int ks = 0; ks < 4; ks++) bf[ks] = cb8[(nt * 4 + ks) * 64 + l];
      float mm = -3.0e38f;
#pragma unroll
      for (int mt = 0; mt < 4; mt++) {
        f32x4 acc = {0.f, 0.f, 0.f, 0.f};
#pragma unroll
        for (int ks = 0; ks < 4; ks++)
          acc = __builtin_amdgcn_mfma_f32_16x16x32_bf16(a[mt][ks], bf[ks], acc, 0, 0, 0);
        mm = fmaxf(mm, fmaxf(fmaxf(acc[0], acc[1]), fmaxf(acc[2], acc[3])));
      }
      mm = fmaxf(mm, __shfl_xor(mm, 16));
      mm = fmaxf(mm, __shfl_xor(mm, 32));
      bmax[i] = mm + cb2[nt * 16 + lr];   // bias is col-constant: add after max
    }
    if (l < 16) {
#pragma unroll
      for (int i = 0; i < 16; i++)
        atomicMax(&gacc[b * 1024 + (wv * 16 + i) * 16 + l], fenc(bmax[i]));
    }
  }
}

// ---------------- Kernel 5: head MLP 1024 -> 512(relu) -> 512 ----------------
__global__ __launch_bounds__(512)
void k_head(const unsigned* __restrict__ gacc,
            const float* __restrict__ mw1, const float* __restrict__ mb1,
            const float* __restrict__ mw2, const float* __restrict__ mb2,
            float* __restrict__ out) {
  __shared__ float g[1024];
  __shared__ float h[512];
  const int b = blockIdx.x, t = threadIdx.x;
  for (int i = t; i < 1024; i += 512) g[i] = fdec(gacc[b * 1024 + i]);
  __syncthreads();
  float a = mb1[t];
  const float4* wr = (const float4*)(mw1 + (size_t)t * 1024);
  const float4* gv = (const float4*)g;
#pragma unroll 8
  for (int c4 = 0; c4 < 256; c4++) a += dot4(wr[c4], gv[c4]);
  h[t] = fmaxf(a, 0.f);
  __syncthreads();
  float a2 = mb2[t];
  const float4* wr2 = (const float4*)(mw2 + (size_t)t * 512);
  const float4* hv = (const float4*)h;
#pragma unroll 8
  for (int c4 = 0; c4 < 128; c4++) a2 += dot4(wr2[c4], hv[c4]);
  out[(size_t)b * 512 + t] = a2;
}

extern "C" void kernel_launch(void* const* d_in, const int* in_sizes, int n_in,
                              void* d_out, int out_size, void* d_ws, size_t ws_size,
                              hipStream_t stream) {
  const float* pts = (const float*)d_in[0];
  const float* w1  = (const float*)d_in[1];
  const float* b1  = (const float*)d_in[2];
  const float* w2  = (const float*)d_in[3];
  const float* b2  = (const float*)d_in[4];
  const float* w3  = (const float*)d_in[5];
  const float* b3  = (const float*)d_in[6];
  const float* lw1 = (const float*)d_in[7];
  const float* lb1 = (const float*)d_in[8];
  const float* cw1 = (const float*)d_in[9];
  const float* cb1 = (const float*)d_in[10];
  const float* lw2 = (const float*)d_in[11];
  const float* lb2 = (const float*)d_in[12];
  const float* cw2 = (const float*)d_in[13];
  const float* cb2 = (const float*)d_in[14];
  const float* mw1 = (const float*)d_in[15];
  const float* mb1 = (const float*)d_in[16];
  const float* mw2 = (const float*)d_in[17];
  const float* mb2 = (const float*)d_in[18];

  char* ws = (char*)d_ws;
  int*      idx  = (int*)(ws);                                    // 2 MB
  float*    x0   = (float*)(ws + 2097152);                        // 1.5 MB
  float*    h3   = (float*)(ws + 2097152 + 1572864);              // 8 MB
  float*    z    = (float*)(ws + 2097152 + 1572864 + 8388608);    // 16 MB
  unsigned* gacc = (unsigned*)(ws + 28835840);                    // 32 KB
  unsigned short* cw2B = (unsigned short*)(ws + 28835840 + 32768);// 256 KB
  float4*   pts4 = (float4*)(ws + 28835840 + 32768 + 262144);     // 512 KB

  hipMemsetAsync(gacc, 0, NBATCH * 1024 * sizeof(unsigned), stream);
  k_wb<<<64, 256, 0, stream>>>(cw2, cw2B);
  k_pack<<<(NBATCH * NPTS) / 256, 256, 0, stream>>>(pts, pts4);
  k_knn<<<NBATCH * (NPTS / 128), 512, 0, stream>>>(pts4, idx, x0);
  k_mlp1<<<(NBATCH * NPTS) / 128, 128, 0, stream>>>(x0, w1, b1, w2, b2, w3, b3, h3);
  k_graph1<<<NBATCH * 64, 256, 0, stream>>>(h3, idx, lw1, lb1, cw1, cb1, z);
  k_graph2<<<NBATCH * (NPTS / 64), 256, 0, stream>>>(z, idx, lw2, lb2, cw2B, cb2, gacc);
  k_head<<<NBATCH, 512, 0, stream>>>(gacc, mw1, mb1, mw2, mb2, (float*)d_out);
}

// Round 13
// 507.023 us; speedup vs baseline: 1.3690x; 1.0265x over previous
//
#include <hip/hip_runtime.h>

#define NPTS 4096
#define NBATCH 8

typedef __attribute__((ext_vector_type(8))) short short8v;   // 8 bf16 = 4 VGPR
typedef __attribute__((ext_vector_type(4))) float f32x4;

__device__ __forceinline__ unsigned fenc(float f) {
  unsigned u = __float_as_uint(f);
  return (u & 0x80000000u) ? ~u : (u | 0x80000000u);
}
__device__ __forceinline__ float fdec(unsigned e) {
  unsigned u = (e & 0x80000000u) ? (e ^ 0x80000000u) : ~e;
  return __uint_as_float(u);
}
__device__ __forceinline__ float dot4(float4 a, float4 b) {
  return a.x * b.x + a.y * b.y + a.z * b.z + a.w * b.w;
}
__device__ __forceinline__ unsigned short f2bf(float f) {   // RNE float->bf16
  unsigned u = __float_as_uint(f);
  return (unsigned short)((u + 0x7fffu + ((u >> 16) & 1u)) >> 16);
}

// -------- Kernel 0a: pack cw2 [1024][128] -> bf16 MFMA B-fragments ----------
__global__ __launch_bounds__(256)
void k_wb(const float* __restrict__ cw2, unsigned short* __restrict__ cw2B) {
  int tid = blockIdx.x * 256 + threadIdx.x;   // 0..16383 = (nt*4+ks)*64+l
  int l = tid & 63, ks = (tid >> 6) & 3, nt = tid >> 8;
  int n = nt * 16 + (l & 15);
  int kb = ks * 32 + (l >> 4) * 8;
  const float* src = cw2 + (size_t)n * 128 + kb;
  unsigned short* dst = cw2B + (size_t)tid * 8;
#pragma unroll
  for (int j = 0; j < 8; j++) dst[j] = f2bf(src[j]);
}

// ---------------- Kernel 0b: pack pts -> {x,y,z,|p|^2} float4 ----------------
__global__ __launch_bounds__(256)
void k_pack(const float* __restrict__ pts, float4* __restrict__ pts4) {
  int i = blockIdx.x * 256 + threadIdx.x;     // over NBATCH*NPTS
  float x = pts[3 * i], y = pts[3 * i + 1], z = pts[3 * i + 2];
  pts4[i] = make_float4(x, y, z, x * x + y * y + z * z);
}

// ---------------- Kernel 1 (v3): exact 16-NN + covariance features -----------
// 512 threads = 64 queries x 8 candidate-segments (seg = t>>6, wave-uniform,
// 512 cands each). No sp staging: candidates stream scalarized from global;
// qp + covariance gather hit L2 (pts4 = 64KB/batch). LDS 48KB -> grid 512 =
// 2 blocks/CU = 16 waves/CU (was 8). Exact top-16; td-wins-ties => earlier idx.
__global__ __launch_bounds__(512)
void k_knn(const float4* __restrict__ pts4, int* __restrict__ idxo,
           float* __restrict__ x0) {
  __shared__ float bufd[16][512];             // 32 KB
  __shared__ unsigned short bufi[16][512];    // 16 KB

  const int b = blockIdx.x >> 6;              // 64 chunks of 64 queries
  const int ch = blockIdx.x & 63;
  const float4* pb4 = pts4 + (size_t)b * NPTS;

  const int t = threadIdx.x;
  const int tq = t & 63;
  const int seg = __builtin_amdgcn_readfirstlane(t >> 6);  // wave-uniform
  const int q = ch * 64 + tq;
  const float4 qp = pb4[q];
  const float qs = qp.w;

  float td[16];
  int ti[16];
#pragma unroll
  for (int j = 0; j < 16; j++) { td[j] = 3.0e38f; ti[j] = 0; }
  float worst = 3.0e38f;
  int cnt = 0;

  auto merge = [&]() {
    float bd[16];
    int bi[16];
#pragma unroll
    for (int j = 0; j < 16; j++) {
      bool v = j < cnt;
      float dv = bufd[j][t];
      int iv = (int)bufi[j][t];
      bd[j] = v ? dv : 3.0e38f;
      bi[j] = v ? iv : 0;
    }
    cnt = 0;
    // bitonic sort bd ascending (all indices compile-time)
#pragma unroll
    for (int k = 2; k <= 16; k <<= 1) {
#pragma unroll
      for (int j = k >> 1; j > 0; j >>= 1) {
#pragma unroll
        for (int i = 0; i < 16; i++) {
          int l = i ^ j;
          if (l > i) {
            bool dir = ((i & k) == 0);
            bool sw = dir ? (bd[i] > bd[l]) : (bd[i] < bd[l]);
            float fd = sw ? bd[l] : bd[i];
            float fl = sw ? bd[i] : bd[l];
            int gd = sw ? bi[l] : bi[i];
            int gl = sw ? bi[i] : bi[l];
            bd[i] = fd; bd[l] = fl; bi[i] = gd; bi[l] = gl;
          }
        }
      }
    }
    // cross: keep 16 smallest of {td (asc), bd (asc)}; td wins ties
#pragma unroll
    for (int i = 0; i < 16; i++) {
      int l = 15 - i;
      bool sw = bd[l] < td[i];
      td[i] = sw ? bd[l] : td[i];
      ti[i] = sw ? bi[l] : ti[i];
    }
    // bitonic clean -> ascending
#pragma unroll
    for (int j = 8; j > 0; j >>= 1) {
#pragma unroll
      for (int i = 0; i < 16; i++) {
        int l = i ^ j;
        if (l > i) {
          bool sw = td[i] > td[l];
          float fd = sw ? td[l] : td[i];
          float fl = sw ? td[i] : td[l];
          int gd = sw ? ti[l] : ti[i];
          int gl = sw ? ti[i] : ti[l];
          td[i] = fd; td[l] = fl; ti[i] = gd; ti[l] = gl;
        }
      }
    }
    worst = td[15];
  };

  const float4* ps = pb4 + seg * 512;         // wave-uniform base
  const int base = seg * 512;
  for (int i0 = 0; i0 < 512; i0 += 8) {
    float4 c[8];
#pragma unroll
    for (int u = 0; u < 8; u++) c[u] = ps[i0 + u];   // uniform addr -> scalarized
    float d[8];
#pragma unroll
    for (int u = 0; u < 8; u++)
      d[u] = (qs + c[u].w) - 2.0f * (qp.x * c[u].x + qp.y * c[u].y + qp.z * c[u].z);
#pragma unroll
    for (int u = 0; u < 8; u++) {
      if (d[u] < worst) {               // strict <: earlier index wins ties
        bufd[cnt][t] = d[u];
        bufi[cnt][t] = (unsigned short)(base + i0 + u);
        cnt++;
      }
      if (u == 3 && __any(cnt >= 13)) merge();   // enter<=12, +4 -> cnt<=16
    }
    if (__any(cnt >= 13)) merge();
  }
  if (__any(cnt > 0)) merge();

  // publish per-segment sorted lists, then seg0 threads fold 8 -> 1
#pragma unroll
  for (int j = 0; j < 16; j++) { bufd[j][t] = td[j]; bufi[j][t] = (unsigned short)ti[j]; }
  __syncthreads();
  if (t < 64) {
#pragma unroll
    for (int s = 1; s < 8; s++) {
      float bd[16];
      int bi[16];
#pragma unroll
      for (int j = 0; j < 16; j++) {
        bd[j] = bufd[j][t + 64 * s];
        bi[j] = (int)bufi[j][t + 64 * s];
      }
#pragma unroll
      for (int i = 0; i < 16; i++) {
        int l = 15 - i;
        bool sw = bd[l] < td[i];      // td (earlier segs) wins ties
        td[i] = sw ? bd[l] : td[i];
        ti[i] = sw ? bi[l] : ti[i];
      }
#pragma unroll
      for (int j = 8; j > 0; j >>= 1) {
#pragma unroll
        for (int i = 0; i < 16; i++) {
          int l = i ^ j;
          if (l > i) {
            bool sw2 = td[i] > td[l];
            float fd = sw2 ? td[l] : td[i];
            float fl = sw2 ? td[i] : td[l];
            int gd = sw2 ? ti[l] : ti[i];
            int gl = sw2 ? ti[i] : ti[l];
            td[i] = fd; td[l] = fl; ti[i] = gd; ti[l] = gl;
          }
        }
      }
    }

    // covariance of mean-centered neighbors (gathers hit L2: 64KB/batch)
    float nx[16], ny[16], nz[16];
    float mx = 0.f, my = 0.f, mz = 0.f;
#pragma unroll
    for (int k = 0; k < 16; k++) {
      float4 c = pb4[ti[k]];
      nx[k] = c.x; ny[k] = c.y; nz[k] = c.z;
      mx += c.x; my += c.y; mz += c.z;
    }
    mx *= 0.0625f; my *= 0.0625f; mz *= 0.0625f;
    float c00 = 0, c01 = 0, c02 = 0, c11 = 0, c12 = 0, c22 = 0;
#pragma unroll
    for (int k = 0; k < 16; k++) {
      float dx = nx[k] - mx, dy = ny[k] - my, dz = nz[k] - mz;
      c00 += dx * dx; c01 += dx * dy; c02 += dx * dz;
      c11 += dy * dy; c12 += dy * dz; c22 += dz * dz;
    }
    size_t row = (size_t)b * NPTS + q;
    float* xo = x0 + row * 12;
    xo[0] = qp.x; xo[1] = qp.y; xo[2] = qp.z;
    xo[3] = c00;  xo[4] = c01;  xo[5] = c02;
    xo[6] = c01;  xo[7] = c11;  xo[8] = c12;
    xo[9] = c02;  xo[10] = c12; xo[11] = c22;
    int* io = idxo + row * 16;
#pragma unroll
    for (int k = 0; k < 16; k++) io[k] = ti[k];
  }
}

// ---------------- Kernel 2: MLP1 12->64->64->64 (relu each) ------------------
__global__ __launch_bounds__(128)
void k_mlp1(const float* __restrict__ x0,
            const float* __restrict__ w1, const float* __restrict__ b1,
            const float* __restrict__ w2, const float* __restrict__ b2,
            const float* __restrict__ w3, const float* __restrict__ b3,
            float* __restrict__ h3o) {
  __shared__ float s1[64 * 12], s2[64 * 64], s3[64 * 64];
  __shared__ float sb1[64], sb2[64], sb3[64];
  for (int i = threadIdx.x; i < 64 * 12; i += 128) s1[i] = w1[i];
  for (int i = threadIdx.x; i < 64 * 64; i += 128) { s2[i] = w2[i]; s3[i] = w3[i]; }
  if (threadIdx.x < 64) {
    sb1[threadIdx.x] = b1[threadIdx.x];
    sb2[threadIdx.x] = b2[threadIdx.x];
    sb3[threadIdx.x] = b3[threadIdx.x];
  }
  __syncthreads();

  size_t p = (size_t)blockIdx.x * 128 + threadIdx.x;
  const float4* xv = (const float4*)(x0 + p * 12);
  float4 xa = xv[0], xb = xv[1], xc = xv[2];

  float h[64];
#pragma unroll
  for (int o = 0; o < 64; o++) {
    const float4* wr = (const float4*)(s1 + o * 12);
    float a = sb1[o] + dot4(wr[0], xa) + dot4(wr[1], xb) + dot4(wr[2], xc);
    h[o] = fmaxf(a, 0.f);
  }
  float g[64];
#pragma unroll
  for (int o = 0; o < 64; o++) {
    float a = sb2[o];
    const float4* wr = (const float4*)(s2 + o * 64);
#pragma unroll
    for (int c4 = 0; c4 < 16; c4++) {
      float4 w = wr[c4];
      a += w.x * h[4 * c4] + w.y * h[4 * c4 + 1] + w.z * h[4 * c4 + 2] + w.w * h[4 * c4 + 3];
    }
    g[o] = fmaxf(a, 0.f);
  }
  float* out = h3o + p * 64;
  for (int o = 0; o < 64; o++) {
    float a = sb3[o];
    const float4* wr = (const float4*)(s3 + o * 64);
#pragma unroll
    for (int c4 = 0; c4 < 16; c4++) {
      float4 w = wr[c4];
      a += w.x * g[4 * c4] + w.y * g[4 * c4 + 1] + w.z * g[4 * c4 + 2] + w.w * g[4 * c4 + 3];
    }
    out[o] = fmaxf(a, 0.f);
  }
}

// -------- Kernel 3 (v2): 64-point tile, 4 threads/point, 8 waves/CU ----------
__global__ __launch_bounds__(256)
void k_graph1(const float* __restrict__ h3, const int* __restrict__ idx,
              const float* __restrict__ lw1, const float* __restrict__ lb1,
              const float* __restrict__ cw1, const float* __restrict__ cb1,
              float* __restrict__ z) {
  __shared__ float smc[64][64];   // [channel][point] 16 KB
  __shared__ float yc[64][64];    // [channel][point] 16 KB

  const int b = blockIdx.x >> 6;
  const int pbase = (blockIdx.x & 63) * 64;
  const int t = threadIdx.x;
  const int pl = t & 63;
  const int cg = __builtin_amdgcn_readfirstlane(t >> 6);   // wave-uniform group

  // Phase A: maxpool 16 channels (cg*16..) of point pl over its 16 neighbors
  {
    size_t p = (size_t)b * NPTS + pbase + pl;
    const int* ip = idx + p * 16;
    float mv[16];
#pragma unroll
    for (int c = 0; c < 16; c++) mv[c] = -3.0e38f;
    for (int k = 0; k < 16; k++) {
      const float4* nb = (const float4*)(h3 + (((size_t)b << 12) + ip[k]) * 64 + cg * 16);
#pragma unroll
      for (int c4 = 0; c4 < 4; c4++) {
        float4 v = nb[c4];
        mv[4 * c4]     = fmaxf(mv[4 * c4], v.x);
        mv[4 * c4 + 1] = fmaxf(mv[4 * c4 + 1], v.y);
        mv[4 * c4 + 2] = fmaxf(mv[4 * c4 + 2], v.z);
        mv[4 * c4 + 3] = fmaxf(mv[4 * c4 + 3], v.w);
      }
    }
#pragma unroll
    for (int c = 0; c < 16; c++) smc[cg * 16 + c][pl] = mv[c];
  }
  __syncthreads();

  // Phase B: y[cg*16+j] = lb1 + lw1_row . m   (weights wave-uniform)
  {
    float m[64];
#pragma unroll
    for (int c = 0; c < 64; c++) m[c] = smc[c][pl];
    for (int j = 0; j < 16; j++) {
      const float* wr = lw1 + (size_t)(cg * 16 + j) * 64;
      float a = lb1[cg * 16 + j];
#pragma unroll
      for (int c = 0; c < 64; c++) a += wr[c] * m[c];
      yc[cg * 16 + j][pl] = a;   // no relu on lw1
    }
  }
  __syncthreads();

  // Phase C: z[cg*32+o] = relu(cb1 + cw1_row . y)
  {
    float y[64];
#pragma unroll
    for (int c = 0; c < 64; c++) y[c] = yc[c][pl];
    size_t p = (size_t)b * NPTS + pbase + pl;
    float* zo = z + p * 128 + cg * 32;
    for (int o4 = 0; o4 < 8; o4++) {
      float r[4];
#pragma unroll
      for (int oi = 0; oi < 4; oi++) {
        int o = o4 * 4 + oi;
        const float* wr = cw1 + (size_t)(cg * 32 + o) * 64;
        float a = cb1[cg * 32 + o];
#pragma unroll
        for (int c = 0; c < 64; c++) a += wr[c] * y[c];
        r[oi] = fmaxf(a, 0.f);
      }
      *(float4*)(zo + o4 * 4) = make_float4(r[0], r[1], r[2], r[3]);
    }
  }
}

// ------ Kernel 4: maxpool(z,idx) -> lw2 (fp32) -> cw2 (bf16 MFMA) -> max -----
__global__ __launch_bounds__(256)
void k_graph2(const float* __restrict__ z, const int* __restrict__ idx,
              const float* __restrict__ lw2, const float* __restrict__ lb2,
              const unsigned short* __restrict__ cw2B, const float* __restrict__ cb2,
              unsigned* __restrict__ gacc) {
  __shared__ float smT[128][64];                    // [channel][point] 32 KB
  __shared__ alignas(16) unsigned short stb[64 * 128];  // bf16, XOR-swizzled 16 KB

  const int b = blockIdx.x >> 6;
  const int pbase = (blockIdx.x & 63) * 64;
  const int t = threadIdx.x;

  // Phase A: neighbor maxpool of z -> smT
  {
    const int pl = t & 63, cg = t >> 6;
    size_t p = (size_t)b * NPTS + pbase + pl;
    const int* ip = idx + p * 16;
    float mv[32];
#pragma unroll
    for (int c = 0; c < 32; c++) mv[c] = -3.0e38f;
    for (int k = 0; k < 16; k++) {
      const float4* nb = (const float4*)(z + ((size_t)b * NPTS + ip[k]) * 128 + cg * 32);
#pragma unroll
      for (int c4 = 0; c4 < 8; c4++) {
        float4 v = nb[c4];
        mv[4 * c4]     = fmaxf(mv[4 * c4], v.x);
        mv[4 * c4 + 1] = fmaxf(mv[4 * c4 + 1], v.y);
        mv[4 * c4 + 2] = fmaxf(mv[4 * c4 + 2], v.z);
        mv[4 * c4 + 3] = fmaxf(mv[4 * c4 + 3], v.w);
      }
    }
#pragma unroll
    for (int c = 0; c < 32; c++) smT[cg * 32 + c][pl] = mv[c];
  }
  __syncthreads();

  // Phase B (fp32): ST[p][o] = lb2[o] + lw2[o][:].m[p][:]; emit bf16 swizzled
  {
    const int pl = t & 63, og = t >> 6;
    float acc[32];
#pragma unroll
    for (int oi = 0; oi < 32; oi++) acc[oi] = lb2[og * 32 + oi];
    for (int cb = 0; cb < 4; cb++) {
      float mr[32];
#pragma unroll
      for (int j = 0; j < 32; j++) mr[j] = smT[cb * 32 + j][pl];
#pragma unroll
      for (int oi = 0; oi < 32; oi++) {
        const float4* wr = (const float4*)(lw2 + (size_t)(og * 32 + oi) * 128 + cb * 32);
#pragma unroll
        for (int j4 = 0; j4 < 8; j4++) {
          float4 w = wr[j4];
          acc[oi] += w.x * mr[4 * j4] + w.y * mr[4 * j4 + 1] + w.z * mr[4 * j4 + 2] + w.w * mr[4 * j4 + 3];
        }
      }
    }
#pragma unroll
    for (int e = 0; e < 4; e++) {
      short8v v;
#pragma unroll
      for (int j = 0; j < 8; j++) v[j] = (short)f2bf(acc[e * 8 + j]);
      int bc = (og * 64 + e * 16) ^ ((pl & 7) << 4);   // byte col, swizzled
      *(short8v*)((char*)stb + pl * 256 + bc) = v;
    }
  }
  __syncthreads();

  // Phase C (bf16 MFMA): U = ST x cw2^T (+cb2); col-max over 64 pts; atomicMax.
  {
    const int wv = t >> 6;          // wave: 16 n-tiles each
    const int l = t & 63;
    const int lr = l & 15;
    const int lg = l >> 4;
    short8v a[4][4];                // [m-tile][k-step]
#pragma unroll
    for (int mt = 0; mt < 4; mt++)
#pragma unroll
      for (int ks = 0; ks < 4; ks++) {
        int row = mt * 16 + lr;
        int bc = (ks * 64 + lg * 16) ^ ((row & 7) << 4);
        a[mt][ks] = *(const short8v*)((const char*)stb + row * 256 + bc);
      }
    const short8v* cb8 = (const short8v*)cw2B;
    float bmax[16];
#pragma unroll
    for (int i = 0; i < 16; i++) {
      const int nt = wv * 16 + i;
      short8v bf[4];
#pragma unroll
      for (int ks = 0; ks < 4; ks++) bf[ks] = cb8[(nt * 4 + ks) * 64 + l];
      float mm = -3.0e38f;
#pragma unroll
      for (int mt = 0; mt < 4; mt++) {
        f32x4 acc = {0.f, 0.f, 0.f, 0.f};
#pragma unroll
        for (int ks = 0; ks < 4; ks++)
          acc = __builtin_amdgcn_mfma_f32_16x16x32_bf16(a[mt][ks], bf[ks], acc, 0, 0, 0);
        mm = fmaxf(mm, fmaxf(fmaxf(acc[0], acc[1]), fmaxf(acc[2], acc[3])));
      }
      mm = fmaxf(mm, __shfl_xor(mm, 16));
      mm = fmaxf(mm, __shfl_xor(mm, 32));
      bmax[i] = mm + cb2[nt * 16 + lr];   // bias is col-constant: add after max
    }
    if (l < 16) {
#pragma unroll
      for (int i = 0; i < 16; i++)
        atomicMax(&gacc[b * 1024 + (wv * 16 + i) * 16 + l], fenc(bmax[i]));
    }
  }
}

// ---------------- Kernel 5: head MLP 1024 -> 512(relu) -> 512 ----------------
__global__ __launch_bounds__(512)
void k_head(const unsigned* __restrict__ gacc,
            const float* __restrict__ mw1, const float* __restrict__ mb1,
            const float* __restrict__ mw2, const float* __restrict__ mb2,
            float* __restrict__ out) {
  __shared__ float g[1024];
  __shared__ float h[512];
  const int b = blockIdx.x, t = threadIdx.x;
  for (int i = t; i < 1024; i += 512) g[i] = fdec(gacc[b * 1024 + i]);
  __syncthreads();
  float a = mb1[t];
  const float4* wr = (const float4*)(mw1 + (size_t)t * 1024);
  const float4* gv = (const float4*)g;
#pragma unroll 8
  for (int c4 = 0; c4 < 256; c4++) a += dot4(wr[c4], gv[c4]);
  h[t] = fmaxf(a, 0.f);
  __syncthreads();
  float a2 = mb2[t];
  const float4* wr2 = (const float4*)(mw2 + (size_t)t * 512);
  const float4* hv = (const float4*)h;
#pragma unroll 8
  for (int c4 = 0; c4 < 128; c4++) a2 += dot4(wr2[c4], hv[c4]);
  out[(size_t)b * 512 + t] = a2;
}

extern "C" void kernel_launch(void* const* d_in, const int* in_sizes, int n_in,
                              void* d_out, int out_size, void* d_ws, size_t ws_size,
                              hipStream_t stream) {
  const float* pts = (const float*)d_in[0];
  const float* w1  = (const float*)d_in[1];
  const float* b1  = (const float*)d_in[2];
  const float* w2  = (const float*)d_in[3];
  const float* b2  = (const float*)d_in[4];
  const float* w3  = (const float*)d_in[5];
  const float* b3  = (const float*)d_in[6];
  const float* lw1 = (const float*)d_in[7];
  const float* lb1 = (const float*)d_in[8];
  const float* cw1 = (const float*)d_in[9];
  const float* cb1 = (const float*)d_in[10];
  const float* lw2 = (const float*)d_in[11];
  const float* lb2 = (const float*)d_in[12];
  const float* cw2 = (const float*)d_in[13];
  const float* cb2 = (const float*)d_in[14];
  const float* mw1 = (const float*)d_in[15];
  const float* mb1 = (const float*)d_in[16];
  const float* mw2 = (const float*)d_in[17];
  const float* mb2 = (const float*)d_in[18];

  char* ws = (char*)d_ws;
  int*      idx  = (int*)(ws);                                    // 2 MB
  float*    x0   = (float*)(ws + 2097152);                        // 1.5 MB
  float*    h3   = (float*)(ws + 2097152 + 1572864);              // 8 MB
  float*    z    = (float*)(ws + 2097152 + 1572864 + 8388608);    // 16 MB
  unsigned* gacc = (unsigned*)(ws + 28835840);                    // 32 KB
  unsigned short* cw2B = (unsigned short*)(ws + 28835840 + 32768);// 256 KB
  float4*   pts4 = (float4*)(ws + 28835840 + 32768 + 262144);     // 512 KB

  hipMemsetAsync(gacc, 0, NBATCH * 1024 * sizeof(unsigned), stream);
  k_wb<<<64, 256, 0, stream>>>(cw2, cw2B);
  k_pack<<<(NBATCH * NPTS) / 256, 256, 0, stream>>>(pts, pts4);
  k_knn<<<NBATCH * (NPTS / 64), 512, 0, stream>>>(pts4, idx, x0);
  k_mlp1<<<(NBATCH * NPTS) / 128, 128, 0, stream>>>(x0, w1, b1, w2, b2, w3, b3, h3);
  k_graph1<<<NBATCH * 64, 256, 0, stream>>>(h3, idx, lw1, lb1, cw1, cb1, z);
  k_graph2<<<NBATCH * (NPTS / 64), 256, 0, stream>>>(z, idx, lw2, lb2, cw2B, cb2, gacc);
  k_head<<<NBATCH, 512, 0, stream>>>(gacc, mw1, mb1, mw2, mb2, (float*)d_out);
}

// Round 15
// 410.130 us; speedup vs baseline: 1.6924x; 1.2362x over previous
//
#include <hip/hip_runtime.h>

#define NPTS 4096
#define NBATCH 8

typedef __attribute__((ext_vector_type(8))) short short8v;   // 8 bf16 = 4 VGPR
typedef __attribute__((ext_vector_type(4))) float f32x4;

__device__ __forceinline__ unsigned fenc(float f) {
  unsigned u = __float_as_uint(f);
  return (u & 0x80000000u) ? ~u : (u | 0x80000000u);
}
__device__ __forceinline__ float fdec(unsigned e) {
  unsigned u = (e & 0x80000000u) ? (e ^ 0x80000000u) : ~e;
  return __uint_as_float(u);
}
__device__ __forceinline__ float dot4(float4 a, float4 b) {
  return a.x * b.x + a.y * b.y + a.z * b.z + a.w * b.w;
}
__device__ __forceinline__ unsigned short f2bf(float f) {   // RNE float->bf16
  unsigned u = __float_as_uint(f);
  return (unsigned short)((u + 0x7fffu + ((u >> 16) & 1u)) >> 16);
}

// -------- Kernel 0a: pack cw2 [1024][128] -> bf16 MFMA B-fragments ----------
__global__ __launch_bounds__(256)
void k_wb(const float* __restrict__ cw2, unsigned short* __restrict__ cw2B) {
  int tid = blockIdx.x * 256 + threadIdx.x;   // 0..16383 = (nt*4+ks)*64+l
  int l = tid & 63, ks = (tid >> 6) & 3, nt = tid >> 8;
  int n = nt * 16 + (l & 15);
  int kb = ks * 32 + (l >> 4) * 8;
  const float* src = cw2 + (size_t)n * 128 + kb;
  unsigned short* dst = cw2B + (size_t)tid * 8;
#pragma unroll
  for (int j = 0; j < 8; j++) dst[j] = f2bf(src[j]);
}

// ---------------- Kernel 0b: pack pts -> {x,y,z,|p|^2} float4 ----------------
__global__ __launch_bounds__(256)
void k_pack(const float* __restrict__ pts, float4* __restrict__ pts4) {
  int i = blockIdx.x * 256 + threadIdx.x;     // over NBATCH*NPTS
  float x = pts[3 * i], y = pts[3 * i + 1], z = pts[3 * i + 2];
  pts4[i] = make_float4(x, y, z, x * x + y * y + z * z);
}

// ---- Kernel 0c: transpose head weight [512][cin] -> [cin][512] --------------
__global__ __launch_bounds__(256)
void k_trh(const float* __restrict__ src, float* __restrict__ dst, int cin) {
  int idx = blockIdx.x * 256 + threadIdx.x;   // over cin*512
  int c = idx >> 9, o = idx & 511;
  dst[idx] = src[o * cin + c];
}

// ---------------- Kernel 1 (v3): exact 16-NN + covariance features -----------
// 512 threads = 64 queries x 8 candidate-segments (verified r13: 120us).
__global__ __launch_bounds__(512)
void k_knn(const float4* __restrict__ pts4, int* __restrict__ idxo,
           float* __restrict__ x0) {
  __shared__ float bufd[16][512];             // 32 KB
  __shared__ unsigned short bufi[16][512];    // 16 KB

  const int b = blockIdx.x >> 6;              // 64 chunks of 64 queries
  const int ch = blockIdx.x & 63;
  const float4* pb4 = pts4 + (size_t)b * NPTS;

  const int t = threadIdx.x;
  const int tq = t & 63;
  const int seg = __builtin_amdgcn_readfirstlane(t >> 6);  // wave-uniform
  const int q = ch * 64 + tq;
  const float4 qp = pb4[q];
  const float qs = qp.w;

  float td[16];
  int ti[16];
#pragma unroll
  for (int j = 0; j < 16; j++) { td[j] = 3.0e38f; ti[j] = 0; }
  float worst = 3.0e38f;
  int cnt = 0;

  auto merge = [&]() {
    float bd[16];
    int bi[16];
#pragma unroll
    for (int j = 0; j < 16; j++) {
      bool v = j < cnt;
      float dv = bufd[j][t];
      int iv = (int)bufi[j][t];
      bd[j] = v ? dv : 3.0e38f;
      bi[j] = v ? iv : 0;
    }
    cnt = 0;
#pragma unroll
    for (int k = 2; k <= 16; k <<= 1) {
#pragma unroll
      for (int j = k >> 1; j > 0; j >>= 1) {
#pragma unroll
        for (int i = 0; i < 16; i++) {
          int l = i ^ j;
          if (l > i) {
            bool dir = ((i & k) == 0);
            bool sw = dir ? (bd[i] > bd[l]) : (bd[i] < bd[l]);
            float fd = sw ? bd[l] : bd[i];
            float fl = sw ? bd[i] : bd[l];
            int gd = sw ? bi[l] : bi[i];
            int gl = sw ? bi[i] : bi[l];
            bd[i] = fd; bd[l] = fl; bi[i] = gd; bi[l] = gl;
          }
        }
      }
    }
#pragma unroll
    for (int i = 0; i < 16; i++) {
      int l = 15 - i;
      bool sw = bd[l] < td[i];
      td[i] = sw ? bd[l] : td[i];
      ti[i] = sw ? bi[l] : ti[i];
    }
#pragma unroll
    for (int j = 8; j > 0; j >>= 1) {
#pragma unroll
      for (int i = 0; i < 16; i++) {
        int l = i ^ j;
        if (l > i) {
          bool sw = td[i] > td[l];
          float fd = sw ? td[l] : td[i];
          float fl = sw ? td[i] : td[l];
          int gd = sw ? ti[l] : ti[i];
          int gl = sw ? ti[i] : ti[l];
          td[i] = fd; td[l] = fl; ti[i] = gd; ti[l] = gl;
        }
      }
    }
    worst = td[15];
  };

  const float4* ps = pb4 + seg * 512;         // wave-uniform base
  const int base = seg * 512;
  for (int i0 = 0; i0 < 512; i0 += 8) {
    float4 c[8];
#pragma unroll
    for (int u = 0; u < 8; u++) c[u] = ps[i0 + u];   // uniform addr -> scalarized
    float d[8];
#pragma unroll
    for (int u = 0; u < 8; u++)
      d[u] = (qs + c[u].w) - 2.0f * (qp.x * c[u].x + qp.y * c[u].y + qp.z * c[u].z);
#pragma unroll
    for (int u = 0; u < 8; u++) {
      if (d[u] < worst) {               // strict <: earlier index wins ties
        bufd[cnt][t] = d[u];
        bufi[cnt][t] = (unsigned short)(base + i0 + u);
        cnt++;
      }
      if (u == 3 && __any(cnt >= 13)) merge();   // enter<=12, +4 -> cnt<=16
    }
    if (__any(cnt >= 13)) merge();
  }
  if (__any(cnt > 0)) merge();

  // publish per-segment sorted lists, then seg0 threads fold 8 -> 1
#pragma unroll
  for (int j = 0; j < 16; j++) { bufd[j][t] = td[j]; bufi[j][t] = (unsigned short)ti[j]; }
  __syncthreads();
  if (t < 64) {
#pragma unroll
    for (int s = 1; s < 8; s++) {
      float bd[16];
      int bi[16];
#pragma unroll
      for (int j = 0; j < 16; j++) {
        bd[j] = bufd[j][t + 64 * s];
        bi[j] = (int)bufi[j][t + 64 * s];
      }
#pragma unroll
      for (int i = 0; i < 16; i++) {
        int l = 15 - i;
        bool sw = bd[l] < td[i];      // td (earlier segs) wins ties
        td[i] = sw ? bd[l] : td[i];
        ti[i] = sw ? bi[l] : ti[i];
      }
#pragma unroll
      for (int j = 8; j > 0; j >>= 1) {
#pragma unroll
        for (int i = 0; i < 16; i++) {
          int l = i ^ j;
          if (l > i) {
            bool sw2 = td[i] > td[l];
            float fd = sw2 ? td[l] : td[i];
            float fl = sw2 ? td[i] : td[l];
            int gd = sw2 ? ti[l] : ti[i];
            int gl = sw2 ? ti[i] : ti[l];
            td[i] = fd; td[l] = fl; ti[i] = gd; ti[l] = gl;
          }
        }
      }
    }

    // covariance of mean-centered neighbors (gathers hit L2: 64KB/batch)
    float nx[16], ny[16], nz[16];
    float mx = 0.f, my = 0.f, mz = 0.f;
#pragma unroll
    for (int k = 0; k < 16; k++) {
      float4 c = pb4[ti[k]];
      nx[k] = c.x; ny[k] = c.y; nz[k] = c.z;
      mx += c.x; my += c.y; mz += c.z;
    }
    mx *= 0.0625f; my *= 0.0625f; mz *= 0.0625f;
    float c00 = 0, c01 = 0, c02 = 0, c11 = 0, c12 = 0, c22 = 0;
#pragma unroll
    for (int k = 0; k < 16; k++) {
      float dx = nx[k] - mx, dy = ny[k] - my, dz = nz[k] - mz;
      c00 += dx * dx; c01 += dx * dy; c02 += dx * dz;
      c11 += dy * dy; c12 += dy * dz; c22 += dz * dz;
    }
    size_t row = (size_t)b * NPTS + q;
    float* xo = x0 + row * 12;
    xo[0] = qp.x; xo[1] = qp.y; xo[2] = qp.z;
    xo[3] = c00;  xo[4] = c01;  xo[5] = c02;
    xo[6] = c01;  xo[7] = c11;  xo[8] = c12;
    xo[9] = c02;  xo[10] = c12; xo[11] = c22;
    int* io = idxo + row * 16;
#pragma unroll
    for (int k = 0; k < 16; k++) io[k] = ti[k];
  }
}

// ------- Kernel 2 (v2): MLP1 12->64->64->64, 64-pt tile, 4 thr/pt -----------
// 512 blocks x 256 threads. LDS [ch][pt] staging; weights wave-uniform scalar.
__global__ __launch_bounds__(256)
void k_mlp1(const float* __restrict__ x0,
            const float* __restrict__ w1, const float* __restrict__ b1,
            const float* __restrict__ w2, const float* __restrict__ b2,
            const float* __restrict__ w3, const float* __restrict__ b3,
            float* __restrict__ h3o) {
  __shared__ float xs[12][64];    // 3 KB
  __shared__ float h1[64][64];    // 16 KB
  __shared__ float h2[64][64];    // 16 KB

  const int b = blockIdx.x >> 6;
  const int pbase = (blockIdx.x & 63) * 64;
  const int t = threadIdx.x;
  const int pl = t & 63;
  const int cg = __builtin_amdgcn_readfirstlane(t >> 6);   // wave-uniform

  // stage x0 tile (64 pts x 12) -> xs[ch][pt]
  {
    const float* xt = x0 + ((size_t)b * NPTS + pbase) * 12;
    for (int e = t; e < 768; e += 256) xs[e % 12][e / 12] = xt[e];
  }
  __syncthreads();

  // layer 1: 12 -> 64 (relu)
  {
    float x[12];
#pragma unroll
    for (int c = 0; c < 12; c++) x[c] = xs[c][pl];
    for (int j = 0; j < 16; j++) {
      int o = cg * 16 + j;
      const float* wr = w1 + (size_t)o * 12;
      float a = b1[o];
#pragma unroll
      for (int c = 0; c < 12; c++) a += wr[c] * x[c];
      h1[o][pl] = fmaxf(a, 0.f);
    }
  }
  __syncthreads();

  // layer 2: 64 -> 64 (relu)
  {
    float m[64];
#pragma unroll
    for (int c = 0; c < 64; c++) m[c] = h1[c][pl];
    for (int j = 0; j < 16; j++) {
      int o = cg * 16 + j;
      const float* wr = w2 + (size_t)o * 64;
      float a = b2[o];
#pragma unroll
      for (int c = 0; c < 64; c++) a += wr[c] * m[c];
      h2[o][pl] = fmaxf(a, 0.f);
    }
  }
  __syncthreads();

  // layer 3: 64 -> 64 (relu), write h3[point][cg*16..]
  {
    float m[64];
#pragma unroll
    for (int c = 0; c < 64; c++) m[c] = h2[c][pl];
    float* out = h3o + ((size_t)b * NPTS + pbase + pl) * 64 + cg * 16;
    for (int j4 = 0; j4 < 4; j4++) {
      float r[4];
#pragma unroll
      for (int ji = 0; ji < 4; ji++) {
        int o = cg * 16 + j4 * 4 + ji;
        const float* wr = w3 + (size_t)o * 64;
        float a = b3[o];
#pragma unroll
        for (int c = 0; c < 64; c++) a += wr[c] * m[c];
        r[ji] = fmaxf(a, 0.f);
      }
      *(float4*)(out + j4 * 4) = make_float4(r[0], r[1], r[2], r[3]);
    }
  }
}

// -------- Kernel 3 (v2): 64-point tile, 4 threads/point (verified r12) -------
__global__ __launch_bounds__(256)
void k_graph1(const float* __restrict__ h3, const int* __restrict__ idx,
              const float* __restrict__ lw1, const float* __restrict__ lb1,
              const float* __restrict__ cw1, const float* __restrict__ cb1,
              float* __restrict__ z) {
  __shared__ float smc[64][64];   // [channel][point] 16 KB
  __shared__ float yc[64][64];    // [channel][point] 16 KB

  const int b = blockIdx.x >> 6;
  const int pbase = (blockIdx.x & 63) * 64;
  const int t = threadIdx.x;
  const int pl = t & 63;
  const int cg = __builtin_amdgcn_readfirstlane(t >> 6);   // wave-uniform group

  {
    size_t p = (size_t)b * NPTS + pbase + pl;
    const int* ip = idx + p * 16;
    float mv[16];
#pragma unroll
    for (int c = 0; c < 16; c++) mv[c] = -3.0e38f;
    for (int k = 0; k < 16; k++) {
      const float4* nb = (const float4*)(h3 + (((size_t)b << 12) + ip[k]) * 64 + cg * 16);
#pragma unroll
      for (int c4 = 0; c4 < 4; c4++) {
        float4 v = nb[c4];
        mv[4 * c4]     = fmaxf(mv[4 * c4], v.x);
        mv[4 * c4 + 1] = fmaxf(mv[4 * c4 + 1], v.y);
        mv[4 * c4 + 2] = fmaxf(mv[4 * c4 + 2], v.z);
        mv[4 * c4 + 3] = fmaxf(mv[4 * c4 + 3], v.w);
      }
    }
#pragma unroll
    for (int c = 0; c < 16; c++) smc[cg * 16 + c][pl] = mv[c];
  }
  __syncthreads();

  {
    float m[64];
#pragma unroll
    for (int c = 0; c < 64; c++) m[c] = smc[c][pl];
    for (int j = 0; j < 16; j++) {
      const float* wr = lw1 + (size_t)(cg * 16 + j) * 64;
      float a = lb1[cg * 16 + j];
#pragma unroll
      for (int c = 0; c < 64; c++) a += wr[c] * m[c];
      yc[cg * 16 + j][pl] = a;   // no relu on lw1
    }
  }
  __syncthreads();

  {
    float y[64];
#pragma unroll
    for (int c = 0; c < 64; c++) y[c] = yc[c][pl];
    size_t p = (size_t)b * NPTS + pbase + pl;
    float* zo = z + p * 128 + cg * 32;
    for (int o4 = 0; o4 < 8; o4++) {
      float r[4];
#pragma unroll
      for (int oi = 0; oi < 4; oi++) {
        int o = o4 * 4 + oi;
        const float* wr = cw1 + (size_t)(cg * 32 + o) * 64;
        float a = cb1[cg * 32 + o];
#pragma unroll
        for (int c = 0; c < 64; c++) a += wr[c] * y[c];
        r[oi] = fmaxf(a, 0.f);
      }
      *(float4*)(zo + o4 * 4) = make_float4(r[0], r[1], r[2], r[3]);
    }
  }
}

// ------ Kernel 4: maxpool(z,idx) -> lw2 (fp32) -> cw2 (bf16 MFMA) -> max -----
__global__ __launch_bounds__(256)
void k_graph2(const float* __restrict__ z, const int* __restrict__ idx,
              const float* __restrict__ lw2, const float* __restrict__ lb2,
              const unsigned short* __restrict__ cw2B, const float* __restrict__ cb2,
              unsigned* __restrict__ gacc) {
  __shared__ float smT[128][64];                    // [channel][point] 32 KB
  __shared__ alignas(16) unsigned short stb[64 * 128];  // bf16, XOR-swizzled 16 KB

  const int b = blockIdx.x >> 6;
  const int pbase = (blockIdx.x & 63) * 64;
  const int t = threadIdx.x;

  {
    const int pl = t & 63, cg = t >> 6;
    size_t p = (size_t)b * NPTS + pbase + pl;
    const int* ip = idx + p * 16;
    float mv[32];
#pragma unroll
    for (int c = 0; c < 32; c++) mv[c] = -3.0e38f;
    for (int k = 0; k < 16; k++) {
      const float4* nb = (const float4*)(z + ((size_t)b * NPTS + ip[k]) * 128 + cg * 32);
#pragma unroll
      for (int c4 = 0; c4 < 8; c4++) {
        float4 v = nb[c4];
        mv[4 * c4]     = fmaxf(mv[4 * c4], v.x);
        mv[4 * c4 + 1] = fmaxf(mv[4 * c4 + 1], v.y);
        mv[4 * c4 + 2] = fmaxf(mv[4 * c4 + 2], v.z);
        mv[4 * c4 + 3] = fmaxf(mv[4 * c4 + 3], v.w);
      }
    }
#pragma unroll
    for (int c = 0; c < 32; c++) smT[cg * 32 + c][pl] = mv[c];
  }
  __syncthreads();

  {
    const int pl = t & 63, og = t >> 6;
    float acc[32];
#pragma unroll
    for (int oi = 0; oi < 32; oi++) acc[oi] = lb2[og * 32 + oi];
    for (int cb = 0; cb < 4; cb++) {
      float mr[32];
#pragma unroll
      for (int j = 0; j < 32; j++) mr[j] = smT[cb * 32 + j][pl];
#pragma unroll
      for (int oi = 0; oi < 32; oi++) {
        const float4* wr = (const float4*)(lw2 + (size_t)(og * 32 + oi) * 128 + cb * 32);
#pragma unroll
        for (int j4 = 0; j4 < 8; j4++) {
          float4 w = wr[j4];
          acc[oi] += w.x * mr[4 * j4] + w.y * mr[4 * j4 + 1] + w.z * mr[4 * j4 + 2] + w.w * mr[4 * j4 + 3];
        }
      }
    }
#pragma unroll
    for (int e = 0; e < 4; e++) {
      short8v v;
#pragma unroll
      for (int j = 0; j < 8; j++) v[j] = (short)f2bf(acc[e * 8 + j]);
      int bc = (og * 64 + e * 16) ^ ((pl & 7) << 4);   // byte col, swizzled
      *(short8v*)((char*)stb + pl * 256 + bc) = v;
    }
  }
  __syncthreads();

  {
    const int wv = t >> 6;          // wave: 16 n-tiles each
    const int l = t & 63;
    const int lr = l & 15;
    const int lg = l >> 4;
    short8v a[4][4];                // [m-tile][k-step]
#pragma unroll
    for (int mt = 0; mt < 4; mt++)
#pragma unroll
      for (int ks = 0; ks < 4; ks++) {
        int row = mt * 16 + lr;
        int bc = (ks * 64 + lg * 16) ^ ((row & 7) << 4);
        a[mt][ks] = *(const short8v*)((const char*)stb + row * 256 + bc);
      }
    const short8v* cb8 = (const short8v*)cw2B;
    float bmax[16];
#pragma unroll
    for (int i = 0; i < 16; i++) {
      const int nt = wv * 16 + i;
      short8v bf[4];
#pragma unroll
      for (int ks = 0; ks < 4; ks++) bf[ks] = cb8[(nt * 4 + ks) * 64 + l];
      float mm = -3.0e38f;
#pragma unroll
      for (int mt = 0; mt < 4; mt++) {
        f32x4 acc = {0.f, 0.f, 0.f, 0.f};
#pragma unroll
        for (int ks = 0; ks < 4; ks++)
          acc = __builtin_amdgcn_mfma_f32_16x16x32_bf16(a[mt][ks], bf[ks], acc, 0, 0, 0);
        mm = fmaxf(mm, fmaxf(fmaxf(acc[0], acc[1]), fmaxf(acc[2], acc[3])));
      }
      mm = fmaxf(mm, __shfl_xor(mm, 16));
      mm = fmaxf(mm, __shfl_xor(mm, 32));
      bmax[i] = mm + cb2[nt * 16 + lr];   // bias is col-constant: add after max
    }
    if (l < 16) {
#pragma unroll
      for (int i = 0; i < 16; i++)
        atomicMax(&gacc[b * 1024 + (wv * 16 + i) * 16 + l], fenc(bmax[i]));
    }
  }
}

// ------ Kernel 5a: head layer1 1024 -> 512 (relu), 8 workers/output ----------
// grid = NBATCH x 8 chunks; block 512 = 64 outputs x 8 workers. mw1T coalesced.
__global__ __launch_bounds__(512)
void k_head1(const unsigned* __restrict__ gacc, const float* __restrict__ mw1T,
             const float* __restrict__ mb1, float* __restrict__ hbuf) {
  __shared__ float gs[1024];
  __shared__ float psum[8][64];
  const int b = blockIdx.x >> 3;
  const int og = blockIdx.x & 7;
  const int t = threadIdx.x;
  const int o = t & 63;
  const int w = __builtin_amdgcn_readfirstlane(t >> 6);   // wave-uniform
  for (int i = t; i < 1024; i += 512) gs[i] = fdec(gacc[b * 1024 + i]);
  __syncthreads();
  float a = 0.f;
  const float* wp = mw1T + (size_t)(w * 128) * 512 + og * 64 + o;
#pragma unroll 8
  for (int c = 0; c < 128; c++) a += wp[c * 512] * gs[w * 128 + c];
  psum[w][o] = a;
  __syncthreads();
  if (t < 64) {
    float s = mb1[og * 64 + t];
#pragma unroll
    for (int ww = 0; ww < 8; ww++) s += psum[ww][t];
    hbuf[b * 512 + og * 64 + t] = fmaxf(s, 0.f);
  }
}

// ------ Kernel 5b: head layer2 512 -> 512, 8 workers/output ------------------
__global__ __launch_bounds__(512)
void k_head2(const float* __restrict__ hbuf, const float* __restrict__ mw2T,
             const float* __restrict__ mb2, float* __restrict__ out) {
  __shared__ float hs[512];
  __shared__ float psum[8][64];
  const int b = blockIdx.x >> 3;
  const int og = blockIdx.x & 7;
  const int t = threadIdx.x;
  const int o = t & 63;
  const int w = __builtin_amdgcn_readfirstlane(t >> 6);   // wave-uniform
  if (t < 512) hs[t] = hbuf[b * 512 + t];
  __syncthreads();
  float a = 0.f;
  const float* wp = mw2T + (size_t)(w * 64) * 512 + og * 64 + o;
#pragma unroll 8
  for (int c = 0; c < 64; c++) a += wp[c * 512] * hs[w * 64 + c];
  psum[w][o] = a;
  __syncthreads();
  if (t < 64) {
    float s = mb2[og * 64 + t];
#pragma unroll
    for (int ww = 0; ww < 8; ww++) s += psum[ww][t];
    out[(size_t)b * 512 + og * 64 + t] = s;
  }
}

extern "C" void kernel_launch(void* const* d_in, const int* in_sizes, int n_in,
                              void* d_out, int out_size, void* d_ws, size_t ws_size,
                              hipStream_t stream) {
  const float* pts = (const float*)d_in[0];
  const float* w1  = (const float*)d_in[1];
  const float* b1  = (const float*)d_in[2];
  const float* w2  = (const float*)d_in[3];
  const float* b2  = (const float*)d_in[4];
  const float* w3  = (const float*)d_in[5];
  const float* b3  = (const float*)d_in[6];
  const float* lw1 = (const float*)d_in[7];
  const float* lb1 = (const float*)d_in[8];
  const float* cw1 = (const float*)d_in[9];
  const float* cb1 = (const float*)d_in[10];
  const float* lw2 = (const float*)d_in[11];
  const float* lb2 = (const float*)d_in[12];
  const float* cw2 = (const float*)d_in[13];
  const float* cb2 = (const float*)d_in[14];
  const float* mw1 = (const float*)d_in[15];
  const float* mb1 = (const float*)d_in[16];
  const float* mw2 = (const float*)d_in[17];
  const float* mb2 = (const float*)d_in[18];

  char* ws = (char*)d_ws;
  int*      idx  = (int*)(ws);                                    // 2 MB
  float*    x0   = (float*)(ws + 2097152);                        // 1.5 MB
  float*    h3   = (float*)(ws + 2097152 + 1572864);              // 8 MB
  float*    z    = (float*)(ws + 2097152 + 1572864 + 8388608);    // 16 MB
  unsigned* gacc = (unsigned*)(ws + 28835840);                    // 32 KB
  unsigned short* cw2B = (unsigned short*)(ws + 28835840 + 32768);// 256 KB
  float4*   pts4 = (float4*)(ws + 28835840 + 32768 + 262144);     // 512 KB
  float*    mw1T = (float*)(ws + 29655040);                       // 2 MB
  float*    mw2T = (float*)(ws + 29655040 + 2097152);             // 1 MB
  float*    hbuf = (float*)(ws + 29655040 + 2097152 + 1048576);   // 16 KB

  hipMemsetAsync(gacc, 0, NBATCH * 1024 * sizeof(unsigned), stream);
  k_wb<<<64, 256, 0, stream>>>(cw2, cw2B);
  k_pack<<<(NBATCH * NPTS) / 256, 256, 0, stream>>>(pts, pts4);
  k_trh<<<2048, 256, 0, stream>>>(mw1, mw1T, 1024);
  k_trh<<<1024, 256, 0, stream>>>(mw2, mw2T, 512);
  k_knn<<<NBATCH * (NPTS / 64), 512, 0, stream>>>(pts4, idx, x0);
  k_mlp1<<<NBATCH * 64, 256, 0, stream>>>(x0, w1, b1, w2, b2, w3, b3, h3);
  k_graph1<<<NBATCH * 64, 256, 0, stream>>>(h3, idx, lw1, lb1, cw1, cb1, z);
  k_graph2<<<NBATCH * (NPTS / 64), 256, 0, stream>>>(z, idx, lw2, lb2, cw2B, cb2, gacc);
  k_head1<<<NBATCH * 8, 512, 0, stream>>>(gacc, mw1T, mb1, hbuf);
  k_head2<<<NBATCH * 8, 512, 0, stream>>>(hbuf, mw2T, mb2, (float*)d_out);
}